// Round 14
// baseline (431.562 us; speedup 1.0000x reference)
//
#include <cstring>          // host memset/memcpy: MUST precede rocprim (its host
#include <cstdio>           // code calls ::memset; without this only the HIP
#include <hip/hip_runtime.h>  // __device__ memset overload is visible -> compile error
#include <rocprim/rocprim.hpp>

// Problem constants
#define ARW_N_NODES   100000
#define ARW_N_EDGES   3200000
#define ARW_N_WALKERS 400000
#define ARW_WLEN      8
#define ARW_LOUT      7
#define ARW_ROW_LEN   6000000           // N_EDGES + N_WALKERS*LOUT
#define ARW_OUT_ELEMS 18000000          // float32 output elements

// CSR build = rocprim stable radix sort (17-bit keys) + histogram/scan for pd.
//
// Scratch inside d_out (18M floats = 72MB), int32 view; staged lifetimes:
//   kb0 @ [0, 3200000)         key double-buffer A (dead after sort)
//   kb1 @ [3200000, 6400000)   key double-buffer B (dead after sort)
//   vb0 @ [6400000, 9600000)   val double-buffer A
//   vb1 @ [12000000, 15200000) val double-buffer B == final cols location
//   tmp @ [15200000, 18000000) rocprim temp (11.2MB; asm's ones region, dead after)
//   deg @ [0, 100000)          post-sort: degree counters (inside dead kb0)
//   tot @ [150000, +98), cb2 @ [150200, +98)
//   pd  @ [1800000, 1900000)   packed (rowptr<<10 | deg) (inside dead kb0)
// If sort result lands in vb0 it is copied to vb1 (vb0 overlaps walk's target
// window [9.2M,12M) at [9.2M,9.6M) -- race otherwise). cols == vb1 always after.
// walk writes: targets [9200000,12000000), roots [3200000,6000000),
//              row1-originals [6000000,9200000)  (vb0/kb1 dead by then).
// asm (last) writes row0 [0,3200000), weights [12M,15.2M), ones [15.2M,18M).
#define ARW_KB0   0
#define ARW_KB1   3200000
#define ARW_VB0   6400000
#define ARW_VB1   12000000
#define ARW_TMP   15200000
#define ARW_DEG   0
#define ARW_TOT2  150000
#define ARW_CB2   150200
#define ARW_PD    1800000

__global__ void AddRandomWalkEdge_16896401342869_kernel() {}

// ---------- 1. copy row/col into sort buffers (vectorized) ----------
__global__ __launch_bounds__(256) void arw16896_copy(const int* __restrict__ ei,
                                                     int* __restrict__ s) {
    int g = blockIdx.x * 256 + threadIdx.x;      // grid covers exactly N_EDGES/4
    ((int4*)(s + ARW_KB0))[g] = ((const int4*)ei)[g];
    ((int4*)(s + ARW_VB0))[g] = ((const int4*)(ei + ARW_N_EDGES))[g];
}

// ---------- 1b. col buffer normalize (only if sort ends in vb0) ----------
__global__ __launch_bounds__(256) void arw16896_ccp(const int* __restrict__ src,
                                                    int* __restrict__ dst) {
    int g = blockIdx.x * 256 + threadIdx.x;
    ((int4*)dst)[g] = ((const int4*)src)[g];
}

// ---------- 2. zero degree counters ----------
__global__ __launch_bounds__(1024) void arw16896_zero(int* __restrict__ s) {
    int i = blockIdx.x * 1024 + threadIdx.x;
    if (i < ARW_N_NODES) s[ARW_DEG + i] = 0;
}

// ---------- 3. degree histogram (global atomics, 400KB table L2-resident) ----------
__global__ __launch_bounds__(256) void arw16896_deg(const int* __restrict__ row,
                                                    int* __restrict__ s) {
    int e = blockIdx.x * 256 + threadIdx.x;      // grid covers exactly N_EDGES
    atomicAdd(&s[ARW_DEG + row[e]], 1);
}

// ---------- 4a. per-chunk totals (98 chunks of 1024 nodes) ----------
__global__ __launch_bounds__(1024) void arw16896_tot(int* __restrict__ s) {
    __shared__ int wsum[16];
    int j = blockIdx.x, tid = threadIdx.x, lane = tid & 63, wid = tid >> 6;
    int idx = j * 1024 + tid;
    int a = (idx < ARW_N_NODES) ? s[ARW_DEG + idx] : 0;
    #pragma unroll
    for (int off = 32; off > 0; off >>= 1) a += __shfl_down(a, off, 64);
    if (lane == 0) wsum[wid] = a;
    __syncthreads();
    if (tid == 0) {
        int t = 0;
        #pragma unroll
        for (int w = 0; w < 16; w++) t += wsum[w];
        s[ARW_TOT2 + j] = t;
    }
}

// ---------- 4b. exclusive scan of 98 chunk totals (1 block) ----------
__global__ __launch_bounds__(128) void arw16896_base(int* __restrict__ s) {
    __shared__ int sm[128];
    int tid = threadIdx.x;
    int v = (tid < 98) ? s[ARW_TOT2 + tid] : 0;
    sm[tid] = v;
    __syncthreads();
    for (int off = 1; off < 128; off <<= 1) {
        int x = 0;
        if (tid >= off) x = sm[tid - off];
        __syncthreads();
        sm[tid] += x;
        __syncthreads();
    }
    if (tid < 98) s[ARW_CB2 + tid] = sm[tid] - v;
}

// ---------- 4c. rowptr: chunk-local scan + base -> packed pd ----------
__global__ __launch_bounds__(1024) void arw16896_ptr(int* __restrict__ s) {
    __shared__ int wsum[16];
    int j = blockIdx.x, tid = threadIdx.x, lane = tid & 63, wid = tid >> 6;
    int idx = j * 1024 + tid;
    int v = (idx < ARW_N_NODES) ? s[ARW_DEG + idx] : 0;
    int sv = v;
    #pragma unroll
    for (int off = 1; off < 64; off <<= 1) {
        int x = __shfl_up(sv, off, 64);
        if (lane >= off) sv += x;
    }
    if (lane == 63) wsum[wid] = sv;
    __syncthreads();
    int pre = 0;
    for (int w = 0; w < wid; w++) pre += wsum[w];
    if (idx < ARW_N_NODES) {
        // packed (rowptr<<10 | deg). rowptr < 3.2M (22 bits); deg Poisson(32) << 1023.
        unsigned rb = (unsigned)(s[ARW_CB2 + j] + pre + sv - v);
        s[ARW_PD + idx] = (int)((rb << 10) | (unsigned)v);
    }
}

// ---------- 5. walks (256 thr) + fused streaming tail ----------
// Walk is miss-throughput bound (~36% HBM BW, VALU 3%): idle BW absorbs the
// row1-originals copy ([6M,9.2M)) and the roots fill ([3.2M,6M)); both regions
// are dead sort buffers by now. cols is always vb1 @ [12M,15.2M).
__global__ __launch_bounds__(256) void arw16896_walk(const float* __restrict__ ru,
                                                     const int* __restrict__ ei,
                                                     const int* __restrict__ s,
                                                     const int* __restrict__ cols,
                                                     float* __restrict__ o) {
    __shared__ float tg[4 * 256 * ARW_LOUT];   // 28 KB: 4 segments of 256x7
    int tid = threadIdx.x;
    int v = blockIdx.x * 256 + tid;
    if (v < ARW_N_NODES) {
        float uu[4][8];
        int cur[4];
        #pragma unroll
        for (int k = 0; k < 4; k++) {
            const float4* rp4 = (const float4*)(ru + (size_t)(v + k * ARW_N_NODES) * 8);
            float4 ra = rp4[0], rb = rp4[1];
            uu[k][0] = ra.x; uu[k][1] = ra.y; uu[k][2] = ra.z; uu[k][3] = ra.w;
            uu[k][4] = rb.x; uu[k][5] = rb.y; uu[k][6] = rb.z; uu[k][7] = rb.w;
        }
        // step 0: all 4 walkers share pd[v]; col loads hit the same row segment
        unsigned pd0 = (unsigned)s[ARW_PD + v];
        int d0  = (int)(pd0 & 1023u);
        int rp0 = (int)(pd0 >> 10);
        #pragma unroll
        for (int k = 0; k < 4; k++) {
            int off = (int)(uu[k][0] * (float)d0);   // f32 mul + trunc == reference
            if (off > d0 - 1) off = d0 - 1;
            int nxt = cols[rp0 + off];               // off=-1 only if d0==0: in-bounds junk
            cur[k] = (d0 > 0) ? nxt : v;
        }
        // steps 1..7: 4 independent chains; batch the 4 pd loads, then 4 col loads
        #pragma unroll
        for (int t = 1; t < ARW_WLEN; t++) {
            unsigned pdk[4];
            #pragma unroll
            for (int k = 0; k < 4; k++) pdk[k] = (unsigned)s[ARW_PD + cur[k]];
            #pragma unroll
            for (int k = 0; k < 4; k++) {
                int d = (int)(pdk[k] & 1023u);
                int off = (int)(uu[k][t] * (float)d);
                if (off > d - 1) off = d - 1;        // d==0 -> off=-1, load stays in-bounds
                int nxt = cols[(int)(pdk[k] >> 10) + off];
                cur[k] = (d > 0) ? nxt : cur[k];
                tg[k * (256 * ARW_LOUT) + tid * ARW_LOUT + (t - 1)] = (float)cur[k];
            }
        }
    }
    __syncthreads();
    int blkN = ARW_N_NODES - blockIdx.x * 256;
    if (blkN > 256) blkN = 256;
    int valid = blkN * ARW_LOUT;
    #pragma unroll
    for (int k = 0; k < 4; k++) {
        int base = ARW_ROW_LEN + ARW_N_EDGES +
                   (k * ARW_N_NODES + blockIdx.x * 256) * ARW_LOUT;
        for (int j = tid; j < valid; j += 256)
            o[base + j] = tg[k * (256 * ARW_LOUT) + j];
    }
    // fused streaming tail (grid-stride over all walk threads)
    int gid = blockIdx.x * 256 + tid;
    int stride = gridDim.x * 256;
    for (int i4 = gid; i4 < ARW_N_EDGES / 4; i4 += stride) {
        int4 r1 = ((const int4*)(ei + ARW_N_EDGES))[i4];
        ((float4*)(o + ARW_ROW_LEN))[i4] =
            make_float4((float)r1.x, (float)r1.y, (float)r1.z, (float)r1.w);
    }
    for (int i4 = gid; i4 < (ARW_N_WALKERS * ARW_LOUT) / 4; i4 += stride) {
        int i = i4 * 4;
        float4 r;
        r.x = (float)(((i    ) / ARW_LOUT) % ARW_N_NODES);
        r.y = (float)(((i + 1) / ARW_LOUT) % ARW_N_NODES);
        r.z = (float)(((i + 2) / ARW_LOUT) % ARW_N_NODES);
        r.w = (float)(((i + 3) / ARW_LOUT) % ARW_N_NODES);
        ((float4*)(o + ARW_N_EDGES))[i4] = r;
    }
}

// ---------- 6. remaining assembly: row0 originals + weights + ones ----------
__global__ __launch_bounds__(256) void arw16896_asm(const int* __restrict__ ei,
                                                    const float* __restrict__ wgt,
                                                    float* __restrict__ o) {
    int i4 = blockIdx.x * blockDim.x + threadIdx.x;
    if (i4 < ARW_N_EDGES / 4) {
        int4 r0 = ((const int4*)ei)[i4];
        float4 wv = ((const float4*)wgt)[i4];
        ((float4*)o)[i4] = make_float4((float)r0.x, (float)r0.y, (float)r0.z, (float)r0.w);
        ((float4*)(o + 2 * ARW_ROW_LEN))[i4] = wv;
    }
    if (i4 < (ARW_N_WALKERS * ARW_LOUT) / 4) {
        ((float4*)(o + 2 * ARW_ROW_LEN + ARW_N_EDGES))[i4] = make_float4(1.f, 1.f, 1.f, 1.f);
    }
}

extern "C" void kernel_launch(void* const* d_in, const int* in_sizes, int n_in,
                              void* d_out, int out_size, void* d_ws, size_t ws_size,
                              hipStream_t stream) {
    const int*   ei  = (const int*)d_in[0];
    const float* wgt = (const float*)d_in[1];
    const float* ru  = (const float*)d_in[2];
    int*   s = (int*)d_out;
    float* o = (float*)d_out;

    unsigned* kb0 = (unsigned*)(s + ARW_KB0);
    unsigned* kb1 = (unsigned*)(s + ARW_KB1);
    int* vb0 = s + ARW_VB0;
    int* vb1 = s + ARW_VB1;

    // 1. stage (row,col) into sort double-buffers
    arw16896_copy<<<ARW_N_EDGES / 4 / 256, 256, 0, stream>>>(ei, s);

    // 2. stable radix sort by 17-bit row key (rocprim, header-only, capture-safe;
    //    temp provided by us -> no allocation inside)
    rocprim::double_buffer<unsigned> keys(kb0, kb1);
    rocprim::double_buffer<int>      vals(vb0, vb1);
    size_t tb = 0;
    hipError_t err;
    err = rocprim::radix_sort_pairs(nullptr, tb, keys, vals,
                                    (unsigned)ARW_N_EDGES, 0, 17, stream);
    (void)err;
    void* tmp = (d_ws != nullptr && tb <= ws_size) ? d_ws : (void*)(s + ARW_TMP);
    err = rocprim::radix_sort_pairs(tmp, tb, keys, vals,
                                    (unsigned)ARW_N_EDGES, 0, 17, stream);
    (void)err;

    // 3. normalize cols to vb1 (vb0 overlaps walk's target window)
    const int* cols = vals.current();
    if (cols != vb1) {
        arw16896_ccp<<<ARW_N_EDGES / 4 / 256, 256, 0, stream>>>(cols, vb1);
        cols = vb1;
    }

    // 4. degree histogram + scan -> packed pd (into dead key buffers)
    arw16896_zero<<<(ARW_N_NODES + 1023) / 1024, 1024, 0, stream>>>(s);
    arw16896_deg <<<ARW_N_EDGES / 256, 256, 0, stream>>>(ei, s);
    arw16896_tot <<<98, 1024, 0, stream>>>(s);
    arw16896_base<<<1, 128, 0, stream>>>(s);
    arw16896_ptr <<<98, 1024, 0, stream>>>(s);

    // 5. walk + 6. assembly
    arw16896_walk<<<(ARW_N_NODES + 255) / 256, 256, 0, stream>>>(ru, ei, s, cols, o);
    arw16896_asm <<<(ARW_N_EDGES / 4 + 255) / 256, 256, 0, stream>>>(ei, wgt, o);
}